// Round 1
// baseline (197.774 us; speedup 1.0000x reference)
//
#include <hip/hip_runtime.h>

// Problem constants
#define BB 256      // batch
#define CCH 512     // channels
#define HW 196      // 14*14 spatial
#define TT 197      // templates_b rows (196 + 1 negative)
#define TROWS 208   // padded T rows (13 * 16)
#define TBK 224     // padded K for templates (7 * 32)
#define KPAD 232    // X LDS row length in shorts (464B rows: 16B aligned, conflict-friendly)
#define TPAD 212    // P LDS row length in shorts (424B rows: bank stride 106%32=10 -> conflict-free 16-lane pattern)

typedef __attribute__((ext_vector_type(8))) short bf16x8;
typedef __attribute__((ext_vector_type(4))) float f32x4;
typedef __attribute__((ext_vector_type(4))) unsigned short us4;

__device__ __forceinline__ unsigned short f2bf(float f) {
    union { float f; unsigned u; } v; v.f = f;
    unsigned r = v.u + 0x7FFFu + ((v.u >> 16) & 1u);   // round-to-nearest-even
    return (unsigned short)(r >> 16);
}
__device__ __forceinline__ float bf2f(unsigned short h) {
    union { unsigned u; float f; } v; v.u = ((unsigned)h) << 16;
    return v.f;
}

// ---- prep: gmax = max(templates_f). Every 14x14 window of the 27x27 base
// contains the base's center peak, so max(sel) == max(templates_f) regardless
// of which templates get selected.
__global__ void prep_gmax(const float* __restrict__ tf, float* __restrict__ wsf) {
    __shared__ float red[256];
    float m = -1e30f;
    for (int i = threadIdx.x; i < HW * HW; i += 256) m = fmaxf(m, tf[i]);
    red[threadIdx.x] = m;
    __syncthreads();
    for (int s = 128; s > 0; s >>= 1) {
        if (threadIdx.x < s) red[threadIdx.x] = fmaxf(red[threadIdx.x], red[threadIdx.x + s]);
        __syncthreads();
    }
    if (threadIdx.x == 0) wsf[0] = red[0];
}

// ---- prep: templates_b * tau -> bf16, zero-padded to 208 x 224
__global__ void prep_tb(const float* __restrict__ tb, unsigned short* __restrict__ tb_bf) {
    int i = blockIdx.x * 256 + threadIdx.x;
    if (i >= TROWS * TBK) return;
    int r = i / TBK, k = i % TBK;
    const float tau = 0.5f / 196.0f;
    float v = (r < TT && k < HW) ? tb[r * HW + k] * tau : 0.0f;
    tb_bf[i] = f2bf(v);
}

// ---- main fused kernel: one workgroup per channel
extern "C" __global__ __launch_bounds__(256, 1)
void fused_main(const float* __restrict__ x, const float* __restrict__ tf,
                const float* __restrict__ pT, const unsigned short* __restrict__ tb_bf,
                const float* __restrict__ wsf,
                float* __restrict__ xm_out, float* __restrict__ mask_out,
                float* __restrict__ loss_out)
{
    extern __shared__ char smem[];
    unsigned short* P  = (unsigned short*)smem;                       // [256][TPAD] bf16 tr
    unsigned short* X  = (unsigned short*)(smem + BB * TPAD * 2);     // [64][KPAD] bf16 x_masked chunk
    float* rA  = (float*)(smem + BB * TPAD * 2 + 64 * KPAD * 2);      // [TROWS]
    float* pTs = rA + TROWS;                                          // [200]
    float* red = pTs + 200;                                           // [8]

    const int c    = blockIdx.x;
    const int tid  = threadIdx.x;
    const int lane = tid & 63;
    const int wave = tid >> 6;
    const float rg = 1.0f / wsf[0];

    if (tid < TT) pTs[tid] = pT[tid];

    const int r  = tid >> 2;               // local batch row 0..63
    const int q  = tid & 3;                // quarter of the 49 float4s per row
    const int qs = (q == 0) ? 0 : (1 + 12 * q);   // {0,13,25,37}
    const int qn = (q == 0) ? 13 : 12;

    const int mh = wave >> 1, nh = wave & 1;
    const int mcnt = mh ? 6 : 7;
    const int l15 = lane & 15, lg = lane >> 4;

    for (int cc = 0; cc < 4; ++cc) {
        // ---- stage: load x rows, argmax, mask, write outputs, bf16 -> LDS
        const int b = cc * 64 + r;
        const size_t rowoff = ((size_t)b * CCH + c) * HW;
        const float* xrow = x + rowoff;

        f32x4 xv[13];
        #pragma unroll
        for (int j = 0; j < 13; ++j)
            if (j < qn) xv[j] = *(const f32x4*)(xrow + (qs + j) * 4);

        float bv = -1e30f; int bi = 0;
        #pragma unroll
        for (int j = 0; j < 13; ++j) if (j < qn) {
            #pragma unroll
            for (int e = 0; e < 4; ++e) {
                float v = xv[j][e];
                int k = (qs + j) * 4 + e;
                if (v > bv) { bv = v; bi = k; }      // strict > keeps first index
            }
        }
        #pragma unroll
        for (int m = 1; m <= 2; m <<= 1) {
            float ov = __shfl_xor(bv, m, 64);
            int   oi = __shfl_xor(bi, m, 64);
            if (ov > bv || (ov == bv && oi < bi)) { bv = ov; bi = oi; }
        }

        const float* selrow = tf + (size_t)bi * HW;
        float* xmrow = xm_out + rowoff;
        float* mkrow = mask_out + rowoff;
        unsigned short* xr = X + r * KPAD;

        #pragma unroll
        for (int j = 0; j < 13; ++j) if (j < qn) {
            f32x4 sel = *(const f32x4*)(selrow + (qs + j) * 4);
            f32x4 mk, xm;
            #pragma unroll
            for (int e = 0; e < 4; ++e) {
                float m = fmaxf(sel[e] * rg - 0.2f, 0.0f) * 5.0f;
                mk[e] = m;
                xm[e] = xv[j][e] * m;
            }
            *(f32x4*)(xmrow + (qs + j) * 4) = xm;
            *(f32x4*)(mkrow + (qs + j) * 4) = mk;
            us4 pk;
            #pragma unroll
            for (int e = 0; e < 4; ++e) pk[e] = f2bf(xm[e]);
            *(us4*)(xr + (qs + j) * 4) = pk;
        }
        if (q == 0) {   // zero-pad k 196..231
            #pragma unroll
            for (int j = 0; j < 9; ++j) {
                us4 z = (us4){0, 0, 0, 0};
                *(us4*)(xr + HW + 4 * j) = z;
            }
        }
        __syncthreads();

        // ---- GEMM: tr[t, b] for this chunk.  A = templates (M=T), B = x (N=b)
        f32x4 acc[7][2];
        #pragma unroll
        for (int mt = 0; mt < 7; ++mt) {
            acc[mt][0] = (f32x4){0.f, 0.f, 0.f, 0.f};
            acc[mt][1] = (f32x4){0.f, 0.f, 0.f, 0.f};
        }
        for (int kt = 0; kt < 7; ++kt) {
            const int kb = kt * 32 + lg * 8;
            bf16x8 bfrag[2];
            #pragma unroll
            for (int nt = 0; nt < 2; ++nt) {
                int n = (nh * 2 + nt) * 16 + l15;
                bfrag[nt] = *(const bf16x8*)(X + n * KPAD + kb);
            }
            #pragma unroll
            for (int mt = 0; mt < 7; ++mt) {
                if (mt < mcnt) {
                    int m = (mh * 7 + mt) * 16 + l15;
                    bf16x8 afrag = *(const bf16x8*)(tb_bf + m * TBK + kb);
                    acc[mt][0] = __builtin_amdgcn_mfma_f32_16x16x32_bf16(afrag, bfrag[0], acc[mt][0], 0, 0, 0);
                    acc[mt][1] = __builtin_amdgcn_mfma_f32_16x16x32_bf16(afrag, bfrag[1], acc[mt][1], 0, 0, 0);
                }
            }
        }
        #pragma unroll
        for (int mt = 0; mt < 7; ++mt) if (mt < mcnt) {
            int t0 = (mh * 7 + mt) * 16 + lg * 4;   // C/D: col=lane&15, row=(lane>>4)*4+reg
            #pragma unroll
            for (int nt = 0; nt < 2; ++nt) {
                int bcol = cc * 64 + (nh * 2 + nt) * 16 + l15;
                us4 pk;
                #pragma unroll
                for (int e = 0; e < 4; ++e) pk[e] = f2bf(acc[mt][nt][e]);
                *(us4*)(P + bcol * TPAD + t0) = pk;
            }
        }
        __syncthreads();
    }

    // ---- softmax over b + MI loss.  tr values are ~1e-4 so no max-subtraction needed.
    if (tid < TT) {
        float A = 0.f;
        const unsigned short* pc = P + tid;
        for (int b = 0; b < BB; ++b) A += __expf(bf2f(pc[b * TPAD]));
        rA[tid] = 1.0f / A;
    }
    __syncthreads();

    const unsigned short* prow = P + tid * TPAD;
    float px = 0.f;
    for (int t = 0; t < TT; ++t) px += pTs[t] * __expf(bf2f(prow[t])) * rA[t];
    const float rpx = 1.0f / px;
    float part = 0.f;
    for (int t = 0; t < TT; ++t) {
        float Pv = __expf(bf2f(prow[t])) * rA[t];
        part += pTs[t] * Pv * __logf(Pv * rpx);
    }
    #pragma unroll
    for (int off = 32; off >= 1; off >>= 1) part += __shfl_xor(part, off, 64);
    if (lane == 0) red[wave] = part;
    __syncthreads();
    if (tid == 0) loss_out[c] = -(red[0] + red[1] + red[2] + red[3]);
}

extern "C" void kernel_launch(void* const* d_in, const int* in_sizes, int n_in,
                              void* d_out, int out_size, void* d_ws, size_t ws_size,
                              hipStream_t stream) {
    const float* x  = (const float*)d_in[0];
    const float* tf = (const float*)d_in[1];
    const float* tb = (const float*)d_in[2];
    const float* pT = (const float*)d_in[3];

    const size_t NOUT = (size_t)BB * CCH * HW;
    float* xm_out = (float*)d_out;
    float* mk_out = xm_out + NOUT;
    float* ls_out = mk_out + NOUT;

    float* wsf = (float*)d_ws;
    unsigned short* tb_bf = (unsigned short*)((char*)d_ws + 64);   // 208*224*2 = 93184 B

    prep_gmax<<<1, 256, 0, stream>>>(tf, wsf);
    prep_tb<<<(TROWS * TBK + 255) / 256, 256, 0, stream>>>(tb, tb_bf);

    const size_t SMEM = (size_t)BB * TPAD * 2 + 64 * KPAD * 2 + (TROWS + 200 + 8) * 4; // 139904
    hipFuncSetAttribute((const void*)fused_main, hipFuncAttributeMaxDynamicSharedMemorySize, (int)SMEM);
    fused_main<<<dim3(CCH), dim3(256), SMEM, stream>>>(x, tf, pT, tb_bf, wsf,
                                                       xm_out, mk_out, ls_out);
}

// Round 2
// 175.418 us; speedup vs baseline: 1.1274x; 1.1274x over previous
//
#include <hip/hip_runtime.h>

// Problem constants
#define BB 256      // batch
#define CCH 512     // channels
#define HW 196      // 14*14 spatial
#define TT 197      // templates_b rows (196 + 1 negative)
#define TROWS 208   // padded T rows (13 * 16)
#define TBK 224     // padded K for templates (7 * 32)
#define KPAD 232    // X LDS row length in shorts (464B rows, 16B aligned)

typedef __attribute__((ext_vector_type(8))) short bf16x8;
typedef __attribute__((ext_vector_type(4))) float f32x4;
typedef __attribute__((ext_vector_type(4))) unsigned short us4;

__device__ __forceinline__ unsigned short f2bf(float f) {
    union { float f; unsigned u; } v; v.f = f;
    unsigned r = v.u + 0x7FFFu + ((v.u >> 16) & 1u);   // round-to-nearest-even
    return (unsigned short)(r >> 16);
}

// ---- prep: gmax = max(templates_f). Every 14x14 window of the 27x27 base
// contains the base's center peak, so max(sel) == max(templates_f).
__global__ void prep_gmax(const float* __restrict__ tf, float* __restrict__ wsf) {
    __shared__ float red[256];
    float m = -1e30f;
    for (int i = threadIdx.x; i < HW * HW; i += 256) m = fmaxf(m, tf[i]);
    red[threadIdx.x] = m;
    __syncthreads();
    for (int s = 128; s > 0; s >>= 1) {
        if (threadIdx.x < s) red[threadIdx.x] = fmaxf(red[threadIdx.x], red[threadIdx.x + s]);
        __syncthreads();
    }
    if (threadIdx.x == 0) wsf[0] = red[0];
}

// ---- prep: templates_b * tau -> bf16, zero-padded to 208 x 224
__global__ void prep_tb(const float* __restrict__ tb, unsigned short* __restrict__ tb_bf) {
    int i = blockIdx.x * 256 + threadIdx.x;
    if (i >= TROWS * TBK) return;
    int r = i / TBK, k = i % TBK;
    const float tau = 0.5f / 196.0f;
    float v = (r < TT && k < HW) ? tb[r * HW + k] * tau : 0.0f;
    tb_bf[i] = f2bf(v);
}

// ---- main fused kernel: one workgroup (1024 threads, 16 waves) per channel.
// tr (208x256) lives entirely in registers: wave w owns batch columns
// w*16..w*16+15, loops all 13 M-tiles -> acc[13] f32x4 per lane.
extern "C" __global__ __launch_bounds__(1024)
void fused_main(const float* __restrict__ x, const float* __restrict__ tf,
                const float* __restrict__ pT, const unsigned short* __restrict__ tb_bf,
                const float* __restrict__ wsf,
                float* __restrict__ xm_out, float* __restrict__ mask_out,
                float* __restrict__ loss_out)
{
    extern __shared__ char smem[];
    unsigned short* X = (unsigned short*)smem;                 // [256][KPAD] bf16 x_masked
    float* s_part = (float*)(smem + BB * KPAD * 2);            // [16][208] per-wave column sums
    float* rAs    = s_part + 16 * TROWS;                       // [208] 1/sum_b exp(tr)
    float* pTs    = rAs + TROWS;                               // [208] p_T zero-padded
    float* red    = pTs + TROWS;                               // [16]

    const int c    = blockIdx.x;
    const int tid  = threadIdx.x;
    const int lane = tid & 63;
    const int w    = tid >> 6;          // wave 0..15
    const int l15  = lane & 15, lg = lane >> 4;
    const float rg = 1.0f / wsf[0];

    if (tid < TROWS) pTs[tid] = (tid < TT) ? pT[tid] : 0.0f;

    // ---- stage: one thread-quad per batch row; interleaved chunks q+4j so each
    // quad's 4 lanes cover one contiguous 64B segment per instruction.
    const int b = tid >> 2;             // 0..255
    const int q = tid & 3;
    const int nch = (q == 0) ? 13 : 12; // q=0 also takes chunk 48

    const size_t rowoff = ((size_t)b * CCH + c) * HW;
    const float* xrow = x + rowoff;

    f32x4 xv[13];
    #pragma unroll
    for (int j = 0; j < 13; ++j)
        if (j < nch) xv[j] = *(const f32x4*)(xrow + (q + 4 * j) * 4);

    float bv = -1e30f; int bi = 0;
    #pragma unroll
    for (int j = 0; j < 13; ++j) if (j < nch) {
        #pragma unroll
        for (int e = 0; e < 4; ++e) {
            float v = xv[j][e];
            int k = (q + 4 * j) * 4 + e;
            if (v > bv) { bv = v; bi = k; }    // per-lane k increases -> strict > keeps first
        }
    }
    #pragma unroll
    for (int m = 1; m <= 2; m <<= 1) {
        float ov = __shfl_xor(bv, m, 64);
        int   oi = __shfl_xor(bi, m, 64);
        if (ov > bv || (ov == bv && oi < bi)) { bv = ov; bi = oi; }
    }

    const float* selrow = tf + (size_t)bi * HW;
    float* xmrow = xm_out + rowoff;
    float* mkrow = mask_out + rowoff;
    unsigned short* xr = X + b * KPAD;

    #pragma unroll
    for (int j = 0; j < 13; ++j) if (j < nch) {
        const int ch = q + 4 * j;
        f32x4 sel = *(const f32x4*)(selrow + ch * 4);
        f32x4 mk, xm;
        #pragma unroll
        for (int e = 0; e < 4; ++e) {
            float m = fmaxf(sel[e] * rg - 0.2f, 0.0f) * 5.0f;
            mk[e] = m;
            xm[e] = xv[j][e] * m;
        }
        *(f32x4*)(xmrow + ch * 4) = xm;
        *(f32x4*)(mkrow + ch * 4) = mk;
        us4 pk;
        #pragma unroll
        for (int e = 0; e < 4; ++e) pk[e] = f2bf(xm[e]);
        *(us4*)(xr + ch * 4) = pk;
    }
    if (q == 0) {   // zero-pad shorts 196..231
        #pragma unroll
        for (int j = 0; j < 9; ++j) {
            us4 z = (us4){0, 0, 0, 0};
            *(us4*)(xr + HW + 4 * j) = z;
        }
    }
    __syncthreads();

    // ---- GEMM: tr[t, b] for this wave's 16 batches, all 208 t in registers.
    f32x4 acc[13];
    #pragma unroll
    for (int mt = 0; mt < 13; ++mt) acc[mt] = (f32x4){0.f, 0.f, 0.f, 0.f};

    const unsigned short* xb = X + (w * 16 + l15) * KPAD;
    for (int kt = 0; kt < 7; ++kt) {
        const int kb = kt * 32 + lg * 8;
        bf16x8 bfrag = *(const bf16x8*)(xb + kb);
        #pragma unroll
        for (int mt = 0; mt < 13; ++mt) {
            bf16x8 afrag = *(const bf16x8*)(tb_bf + (mt * 16 + l15) * TBK + kb);
            acc[mt] = __builtin_amdgcn_mfma_f32_16x16x32_bf16(afrag, bfrag, acc[mt], 0, 0, 0);
        }
    }

    // ---- Phase A: exp in-register, column-sum over this wave's 16 b, cross-wave via LDS
    float* sp = s_part + w * TROWS;
    #pragma unroll
    for (int mt = 0; mt < 13; ++mt) {
        #pragma unroll
        for (int e = 0; e < 4; ++e) acc[mt][e] = __expf(acc[mt][e]);
        f32x4 s = acc[mt];
        #pragma unroll
        for (int m = 1; m <= 8; m <<= 1) {
            #pragma unroll
            for (int e = 0; e < 4; ++e) s[e] += __shfl_xor(s[e], m, 64);
        }
        if (l15 == 0) *(f32x4*)(sp + mt * 16 + lg * 4) = s;
    }
    __syncthreads();
    if (tid < TROWS) {
        float s = 0.f;
        #pragma unroll
        for (int w2 = 0; w2 < 16; ++w2) s += s_part[w2 * TROWS + tid];
        rAs[tid] = 1.0f / s;
    }
    __syncthreads();

    // ---- Phase B: p = exp*rA (in-register), px[b] = sum_t pT*p
    float px = 0.f;
    #pragma unroll
    for (int mt = 0; mt < 13; ++mt) {
        const int t0 = mt * 16 + lg * 4;
        f32x4 ra = *(const f32x4*)(rAs + t0);
        f32x4 pt = *(const f32x4*)(pTs + t0);
        #pragma unroll
        for (int e = 0; e < 4; ++e) {
            float p = acc[mt][e] * ra[e];
            acc[mt][e] = p;
            px += pt[e] * p;
        }
    }
    px += __shfl_xor(px, 16, 64);
    px += __shfl_xor(px, 32, 64);
    const float rpx = 1.0f / px;

    // ---- Phase C: loss partial = sum_t pT * p * log(p/px)
    float part = 0.f;
    #pragma unroll
    for (int mt = 0; mt < 13; ++mt) {
        const int t0 = mt * 16 + lg * 4;
        f32x4 pt = *(const f32x4*)(pTs + t0);
        #pragma unroll
        for (int e = 0; e < 4; ++e) {
            float p = acc[mt][e];
            part += pt[e] * p * __logf(p * rpx);
        }
    }
    #pragma unroll
    for (int off = 32; off >= 1; off >>= 1) part += __shfl_xor(part, off, 64);
    if (lane == 0) red[w] = part;
    __syncthreads();
    if (tid == 0) {
        float s = 0.f;
        #pragma unroll
        for (int w2 = 0; w2 < 16; ++w2) s += red[w2];
        loss_out[c] = -s;
    }
}

extern "C" void kernel_launch(void* const* d_in, const int* in_sizes, int n_in,
                              void* d_out, int out_size, void* d_ws, size_t ws_size,
                              hipStream_t stream) {
    const float* x  = (const float*)d_in[0];
    const float* tf = (const float*)d_in[1];
    const float* tb = (const float*)d_in[2];
    const float* pT = (const float*)d_in[3];

    const size_t NOUT = (size_t)BB * CCH * HW;
    float* xm_out = (float*)d_out;
    float* mk_out = xm_out + NOUT;
    float* ls_out = mk_out + NOUT;

    float* wsf = (float*)d_ws;
    unsigned short* tb_bf = (unsigned short*)((char*)d_ws + 64);   // 208*224*2 = 93184 B

    prep_gmax<<<1, 256, 0, stream>>>(tf, wsf);
    prep_tb<<<(TROWS * TBK + 255) / 256, 256, 0, stream>>>(tb, tb_bf);

    const size_t SMEM = (size_t)BB * KPAD * 2              // X: 118784
                      + 16 * TROWS * 4                     // s_part: 13312
                      + TROWS * 4 + TROWS * 4 + 16 * 4;    // rAs + pTs + red
    hipFuncSetAttribute((const void*)fused_main, hipFuncAttributeMaxDynamicSharedMemorySize, (int)SMEM);
    fused_main<<<dim3(CCH), dim3(1024), SMEM, stream>>>(x, tf, pT, tb_bf, wsf,
                                                        xm_out, mk_out, ls_out);
}